// Round 3
// baseline (94.602 us; speedup 1.0000x reference)
//
#include <hip/hip_runtime.h>
#include <math.h>

#define PI_F 3.14159265358979323846f

// ---------------------------------------------------------------------------
// Setup kernel: one block of 256 threads builds U1 (16x16 complex) and U2
// (4x4 complex), then folds them into packed quadratic forms in d_ws:
//   ws[0..271]   : 136 pairs (i<=j) of (Q1', Q3') interleaved, off-diag doubled
//   ws[272..281] : 10 pairs (i<=j) of Q2', off-diag doubled
//   ws[282..285] : W0, W1, b0, b1
// ---------------------------------------------------------------------------
__global__ void setup_kernel(const float* __restrict__ f1,
                             const float* __restrict__ p1,
                             const float* __restrict__ f2,
                             const float* __restrict__ p2,
                             const float* __restrict__ W,
                             const float* __restrict__ bb,
                             float* __restrict__ ws)
{
    __shared__ float2 M[256];   // current 16x16 product, U = g @ U
    __shared__ float2 tab[16];  // e^{2*pi*i*m/16}
    __shared__ float2 M2[16];   // 4x4 for U2

    const int t = threadIdx.x;
    const int r = t >> 4, c = t & 15;

    if (t < 16) {
        float ang = (2.0f * PI_F / 16.0f) * (float)t;
        tab[t] = make_float2(cosf(ang), sinf(ang));
    }
    M[t] = make_float2((r == c) ? 1.0f : 0.0f, 0.0f);
    __syncthreads();

    // --- QFT16: G[r][k] = e^{2 pi i r k/16}/4 ---
    {
        float2 acc = make_float2(0.0f, 0.0f);
        for (int k = 0; k < 16; ++k) {
            float2 w = tab[(r * k) & 15];
            float2 v = M[k * 16 + c];
            acc.x += w.x * v.x - w.y * v.y;
            acc.y += w.x * v.y + w.y * v.x;
        }
        acc.x *= 0.25f; acc.y *= 0.25f;
        __syncthreads();
        M[t] = acc;
        __syncthreads();
    }
    // --- RZ(f1[i]) on wire i (wire 0 = MSB): diagonal ---
    for (int i = 0; i < 4; ++i) {
        float th = f1[i];
        float ch = cosf(0.5f * th), sh = sinf(0.5f * th);
        int bit = (r >> (3 - i)) & 1;
        float2 d = make_float2(ch, bit ? sh : -sh);   // e^{-+ i th/2}
        float2 m = M[t];
        M[t] = make_float2(d.x * m.x - d.y * m.y, d.x * m.y + d.y * m.x);
        __syncthreads();
    }
    // --- IQFT16 ---
    {
        float2 acc = make_float2(0.0f, 0.0f);
        for (int k = 0; k < 16; ++k) {
            float2 w = tab[(r * k) & 15];   // conj(w)
            float2 v = M[k * 16 + c];
            acc.x += w.x * v.x + w.y * v.y;
            acc.y += w.x * v.y - w.y * v.x;
        }
        acc.x *= 0.25f; acc.y *= 0.25f;
        __syncthreads();
        M[t] = acc;
        __syncthreads();
    }
    // --- entangler blocks at wire 0 and wire 2: CRZ, X, CRX, X ---
    for (int w2 = 0; w2 <= 2; w2 += 2) {
        const int mc = 1 << (3 - w2);   // control-bit mask
        const int mt = mc >> 1;         // target-bit mask
        // CRZ(p1[0]): diagonal
        {
            float th = p1[0];
            float ch = cosf(0.5f * th), sh = sinf(0.5f * th);
            float2 d = (r & mc) ? make_float2(ch, (r & mt) ? sh : -sh)
                                : make_float2(1.0f, 0.0f);
            float2 m = M[t];
            M[t] = make_float2(d.x * m.x - d.y * m.y, d.x * m.y + d.y * m.x);
            __syncthreads();
        }
        // X(w2): row permutation
        {
            float2 v = M[(r ^ mc) * 16 + c];
            __syncthreads();
            M[t] = v;
            __syncthreads();
        }
        // CRX(p1[1]): mixes row pairs when control bit set
        {
            float th = p1[1];
            float ch = cosf(0.5f * th), sh = sinf(0.5f * th);
            float2 own = M[t];
            float2 par = M[(r ^ mt) * 16 + c];
            __syncthreads();
            float2 nv;
            if (r & mc) {
                // nv = ch*own + (-i*sh)*par
                nv.x = ch * own.x + sh * par.y;
                nv.y = ch * own.y - sh * par.x;
            } else {
                nv = own;
            }
            M[t] = nv;
            __syncthreads();
        }
        // X(w2)
        {
            float2 v = M[(r ^ mc) * 16 + c];
            __syncthreads();
            M[t] = v;
            __syncthreads();
        }
    }

    // --- Q1/Q3: Q[i][j] = sum_k s_k * Re(U1[k][i] * conj(U1[k][j])) ---
    {
        float q1 = 0.0f, q3 = 0.0f;
        for (int k = 0; k < 16; ++k) {
            float2 a  = M[k * 16 + r];
            float2 bv = M[k * 16 + c];
            float d = a.x * bv.x + a.y * bv.y;
            q1 += ((k >> 2) & 1) ? -d : d;   // z_signs(wire=1, n=4) -> bit 2
            q3 += (k & 1) ? -d : d;          // z_signs(wire=3, n=4) -> bit 0
        }
        if (r <= c) {
            int p = r * 16 - (r * (r - 1)) / 2 + (c - r);
            float sc = (r == c) ? 1.0f : 2.0f;
            ws[2 * p]     = sc * q1;
            ws[2 * p + 1] = sc * q3;
        }
    }

    // ---------------- U2 (n=2, dim 4) ----------------
    const bool act = (t < 16);
    const int r2 = t >> 2, c2 = t & 3;
    if (act) M2[t] = make_float2((r2 == c2) ? 1.0f : 0.0f, 0.0f);
    __syncthreads();

    // QFT4: w = i^{r*k}, norm 1/2
    {
        float2 acc = make_float2(0.0f, 0.0f);
        if (act) {
            for (int k = 0; k < 4; ++k) {
                int m = (r2 * k) & 3;
                float2 w = (m == 0) ? make_float2(1, 0) :
                           (m == 1) ? make_float2(0, 1) :
                           (m == 2) ? make_float2(-1, 0) : make_float2(0, -1);
                float2 v = M2[k * 4 + c2];
                acc.x += w.x * v.x - w.y * v.y;
                acc.y += w.x * v.y + w.y * v.x;
            }
            acc.x *= 0.5f; acc.y *= 0.5f;
        }
        __syncthreads();
        if (act) M2[t] = acc;
        __syncthreads();
    }
    // RZ(f2[0]) wire0 (bit1), RZ(f2[1]) wire1 (bit0)
    for (int i = 0; i < 2; ++i) {
        float th = f2[i];
        float ch = cosf(0.5f * th), sh = sinf(0.5f * th);
        if (act) {
            int bit = (r2 >> (1 - i)) & 1;
            float2 d = make_float2(ch, bit ? sh : -sh);
            float2 m = M2[t];
            M2[t] = make_float2(d.x * m.x - d.y * m.y, d.x * m.y + d.y * m.x);
        }
        __syncthreads();
    }
    // IQFT4
    {
        float2 acc = make_float2(0.0f, 0.0f);
        if (act) {
            for (int k = 0; k < 4; ++k) {
                int m = (r2 * k) & 3;
                float2 w = (m == 0) ? make_float2(1, 0) :
                           (m == 1) ? make_float2(0, 1) :
                           (m == 2) ? make_float2(-1, 0) : make_float2(0, -1);
                float2 v = M2[k * 4 + c2];
                acc.x += w.x * v.x + w.y * v.y;   // conj(w)
                acc.y += w.x * v.y - w.y * v.x;
            }
            acc.x *= 0.5f; acc.y *= 0.5f;
        }
        __syncthreads();
        if (act) M2[t] = acc;
        __syncthreads();
    }
    // CRZ(p2[0]) wire0: control bit1 (mask2), target bit0 (mask1)
    {
        float th = p2[0];
        float ch = cosf(0.5f * th), sh = sinf(0.5f * th);
        if (act) {
            float2 d = (r2 & 2) ? make_float2(ch, (r2 & 1) ? sh : -sh)
                                : make_float2(1.0f, 0.0f);
            float2 m = M2[t];
            M2[t] = make_float2(d.x * m.x - d.y * m.y, d.x * m.y + d.y * m.x);
        }
        __syncthreads();
    }
    // X wire0 (mask 2)
    {
        float2 v = make_float2(0.0f, 0.0f);
        if (act) v = M2[((r2 ^ 2) * 4) + c2];
        __syncthreads();
        if (act) M2[t] = v;
        __syncthreads();
    }
    // CRX(p2[1]) wire0
    {
        float th = p2[1];
        float ch = cosf(0.5f * th), sh = sinf(0.5f * th);
        float2 nv = make_float2(0.0f, 0.0f);
        if (act) {
            float2 own = M2[t];
            float2 par = M2[((r2 ^ 1) * 4) + c2];
            if (r2 & 2) {
                nv.x = ch * own.x + sh * par.y;
                nv.y = ch * own.y - sh * par.x;
            } else {
                nv = own;
            }
        }
        __syncthreads();
        if (act) M2[t] = nv;
        __syncthreads();
    }
    // X wire0
    {
        float2 v = make_float2(0.0f, 0.0f);
        if (act) v = M2[((r2 ^ 2) * 4) + c2];
        __syncthreads();
        if (act) M2[t] = v;
        __syncthreads();
    }
    // Q2: signs [1,-1,1,-1]
    if (act) {
        float q2v = 0.0f;
        for (int k = 0; k < 4; ++k) {
            float2 a  = M2[k * 4 + r2];
            float2 bv = M2[k * 4 + c2];
            float d = a.x * bv.x + a.y * bv.y;
            q2v += (k & 1) ? -d : d;
        }
        if (r2 <= c2) {
            int p = r2 * 4 - (r2 * (r2 - 1)) / 2 + (c2 - r2);
            ws[272 + p] = ((r2 == c2) ? 1.0f : 2.0f) * q2v;
        }
    }
    if (t == 0) {
        ws[282] = W[0];
        ws[283] = W[1];
        ws[284] = bb[0];
        ws[285] = bb[1];
    }
}

// ---------------------------------------------------------------------------
// Main batch kernel: one row (16 floats) per thread.
// ---------------------------------------------------------------------------
__global__ __launch_bounds__(256) void qfcn_main(const float* __restrict__ x,
                                                 const float* __restrict__ q,
                                                 float* __restrict__ out,
                                                 int B)
{
    int row = blockIdx.x * 256 + threadIdx.x;
    if (row >= B) return;

    const float4* xp = reinterpret_cast<const float4*>(x + (size_t)row * 16);
    float4 a0 = xp[0], a1 = xp[1], a2 = xp[2], a3 = xp[3];
    float xs[16] = {a0.x, a0.y, a0.z, a0.w, a1.x, a1.y, a1.z, a1.w,
                    a2.x, a2.y, a2.z, a2.w, a3.x, a3.y, a3.z, a3.w};

    float ss = 0.0f;
#pragma unroll
    for (int i = 0; i < 16; ++i) ss = fmaf(xs[i], xs[i], ss);

    float e1 = 0.0f, e3 = 0.0f;
    int p = 0;
#pragma unroll
    for (int i = 0; i < 16; ++i) {
#pragma unroll
        for (int j = i; j < 16; ++j) {
            float tp = xs[i] * xs[j];
            e1 = fmaf(q[2 * p],     tp, e1);
            e3 = fmaf(q[2 * p + 1], tp, e3);
            ++p;
        }
    }
    float inv = __builtin_amdgcn_rcpf(ss);
    e1 *= inv;
    e3 *= inv;

    float s0 = __sinf(0.5f * e1), c0 = __cosf(0.5f * e1);
    float s1 = __sinf(0.5f * e3), c1 = __cosf(0.5f * e3);
    float vv[4] = {c0 * c1, c0 * s1, s0 * c1, s0 * s1};

    float e = 0.0f;
    int pp = 0;
#pragma unroll
    for (int i = 0; i < 4; ++i) {
#pragma unroll
        for (int j = i; j < 4; ++j) {
            e = fmaf(q[272 + pp], vv[i] * vv[j], e);
            ++pp;
        }
    }
    float2 o;
    o.x = fmaf(e, q[282], q[284]);
    o.y = fmaf(e, q[283], q[285]);
    reinterpret_cast<float2*>(out)[row] = o;
}

extern "C" void kernel_launch(void* const* d_in, const int* in_sizes, int n_in,
                              void* d_out, int out_size, void* d_ws, size_t ws_size,
                              hipStream_t stream)
{
    const float* x  = (const float*)d_in[0];
    const float* f1 = (const float*)d_in[1];
    const float* p1 = (const float*)d_in[2];
    const float* f2 = (const float*)d_in[3];
    const float* p2 = (const float*)d_in[4];
    const float* W  = (const float*)d_in[5];
    const float* bb = (const float*)d_in[6];
    float* out = (float*)d_out;
    float* ws  = (float*)d_ws;

    int B = in_sizes[0] / 16;

    hipLaunchKernelGGL(setup_kernel, dim3(1), dim3(256), 0, stream,
                       f1, p1, f2, p2, W, bb, ws);
    int blocks = (B + 255) / 256;
    hipLaunchKernelGGL(qfcn_main, dim3(blocks), dim3(256), 0, stream,
                       x, ws, out, B);
}